// Round 7
// baseline (34.124 us; speedup 1.0000x reference)
//
#include <hip/hip_runtime.h>

#define DIM 512
#define NVEC4 (DIM / 4)     // 128 float4 per row
#define LMAX 512            // labels in [0, 512)
#define MAXB 32             // cap on conserved rows per label (mean ~8, P(>32) ~ 1e-10)
#define MAXPAIR (MAXB * (MAXB - 1) / 2)   // 496 per label
#define PAIR_CAP 32768
#define NB_LBL LMAX
#define NB_AUX 32           // 32*256 = 8192 >= S threads for neg validation
#define NB_A (NB_LBL + NB_AUX)   // 544
#define TPB 256
#define GPB (TPB / 16)      // 16-lane groups per block = 16
#define NB_B 512
#define EPS 1e-12f

__device__ __forceinline__ float d4(const float4 a, const float4 b) {
    return a.x * b.x + a.y * b.y + a.z * b.z + a.w * b.w;
}

// ---------------- Kernel A: invn (all rows) + pair/neg list build ----------------
__global__ void __launch_bounds__(TPB)
prep_kernel(const float* __restrict__ E,
            const int* __restrict__ labels,
            const int* __restrict__ graphs,
            const int* __restrict__ cats,
            const int* __restrict__ idx1,
            const int* __restrict__ idx2,
            int n, int S,
            float* __restrict__ invn,
            int* __restrict__ paircnt, int2* __restrict__ pairs,
            int* __restrict__ negcnt, int2* __restrict__ negp,
            float* __restrict__ out) {
    const int tid = threadIdx.x;
    const int grp = tid >> 4, gl = tid & 15;
    const float4* E4 = (const float4*)E;

    // --- flat invn pass: one 16-lane group per row (8704 groups >= n) ---
    {
        int row = blockIdx.x * GPB + grp;
        if (row < n) {
            const float4* A = E4 + (size_t)row * NVEC4;
            float s = 0.0f;
#pragma unroll
            for (int k = 0; k < 8; ++k) {
                float4 x = A[gl + 16 * k];
                s += d4(x, x);
            }
#pragma unroll
            for (int m = 8; m >= 1; m >>= 1) s += __shfl_xor(s, m, 64);
            if (gl == 0) invn[row] = 1.0f / fmaxf(sqrtf(s), EPS);
        }
    }

    if (blockIdx.x < NB_LBL) {
        // --- per-label: scan + local pair enumeration + one global append ---
        __shared__ int idxs[MAXB];
        __shared__ int2 plist[MAXPAIR];
        __shared__ int gcount, pcount, pbase;
        if (tid == 0) { gcount = 0; pcount = 0; }
        __syncthreads();

        const int lbl = blockIdx.x;
        const int4* lab4 = (const int4*)labels;
        int nv4 = n >> 2;
        for (int v = tid; v < nv4; v += TPB) {
            int4 l4 = lab4[v];
            int base = v << 2;
            if (l4.x == lbl && cats[base + 0] < 3) { int p = atomicAdd(&gcount, 1); if (p < MAXB) idxs[p] = base + 0; }
            if (l4.y == lbl && cats[base + 1] < 3) { int p = atomicAdd(&gcount, 1); if (p < MAXB) idxs[p] = base + 1; }
            if (l4.z == lbl && cats[base + 2] < 3) { int p = atomicAdd(&gcount, 1); if (p < MAXB) idxs[p] = base + 2; }
            if (l4.w == lbl && cats[base + 3] < 3) { int p = atomicAdd(&gcount, 1); if (p < MAXB) idxs[p] = base + 3; }
        }
        __syncthreads();

        const int g = min(gcount, MAXB);
        for (int c = tid; c < g * g; c += TPB) {
            int a = c / g, b = c - a * g;
            if (a < b) {
                int ia = idxs[a], ib = idxs[b];
                if (graphs[ia] != graphs[ib])
                    plist[atomicAdd(&pcount, 1)] = make_int2(ia, ib);
            }
        }
        __syncthreads();
        if (tid == 0) pbase = atomicAdd(paircnt, pcount);
        __syncthreads();
        int base = pbase, cnt = pcount;
        for (int k = tid; k < cnt; k += TPB)
            if (base + k < PAIR_CAP) pairs[base + k] = plist[k];
    } else {
        // --- aux blocks: validate negative samples (one thread per sample) ---
        __shared__ int2 nlist[TPB];
        __shared__ int ncount, nbase;
        if (tid == 0) ncount = 0;
        __syncthreads();

        int s = (blockIdx.x - NB_LBL) * TPB + tid;
        if (s < S) {
            int i = idx1[s], j = idx2[s];
            if (graphs[i] != graphs[j] && labels[i] != labels[j] &&
                (cats[i] < 3 || cats[j] < 3))
                nlist[atomicAdd(&ncount, 1)] = make_int2(i, j);
        }
        __syncthreads();
        if (tid == 0) nbase = atomicAdd(negcnt, ncount);
        __syncthreads();
        if (tid < ncount) negp[nbase + tid] = nlist[tid];

        if (blockIdx.x == NB_LBL && tid == 0) out[0] = 0.0f;
    }
}

// Tiny kernel to zero the two list counters (runs before prep).
__global__ void zero_kernel(int* __restrict__ paircnt, int* __restrict__ negcnt) {
    *paircnt = 0; *negcnt = 0;
}

// ---------------- Kernel B: balanced dots + fused finalize ----------------
__global__ void __launch_bounds__(TPB)
dots_kernel(const float* __restrict__ E,
            const float* __restrict__ invn,
            const int* __restrict__ paircnt, const int2* __restrict__ pairs,
            const int* __restrict__ negcnt, const int2* __restrict__ negp,
            float* __restrict__ out) {
    __shared__ float s_acc[2];
    const int tid = threadIdx.x;
    const int grp = tid >> 4, gl = tid & 15;
    if (tid < 2) s_acc[tid] = 0.0f;
    __syncthreads();

    const float4* E4 = (const float4*)E;
    const int np = min(*paircnt, PAIR_CAP);
    const int nn = *negcnt;
    const int total = np + nn;
    const int ggid = blockIdx.x * GPB + grp;
    const int gstride = gridDim.x * GPB;

    float psum = 0.0f, nsum = 0.0f;
    for (int t = ggid; t < total; t += gstride) {
        int2 pr = (t < np) ? pairs[t] : negp[t - np];
        const float4* A = E4 + (size_t)pr.x * NVEC4;
        const float4* B = E4 + (size_t)pr.y * NVEC4;
        float ab = 0.0f;
#pragma unroll
        for (int k = 0; k < 8; ++k)
            ab += d4(A[gl + 16 * k], B[gl + 16 * k]);
#pragma unroll
        for (int m = 8; m >= 1; m >>= 1) ab += __shfl_xor(ab, m, 64);
        if (gl == 0) {
            float sim = ab * invn[pr.x] * invn[pr.y];
            if (t < np) psum += 1.0f - sim;
            else        nsum += fmaxf(sim, 0.0f);   // MARGIN = 0
        }
    }
    if (gl == 0) {
        if (psum != 0.0f) atomicAdd(&s_acc[0], psum);
        if (nsum != 0.0f) atomicAdd(&s_acc[1], nsum);
    }
    __syncthreads();
    if (tid == 0) {
        float v = (np > 0 ? s_acc[0] / (float)np : 0.0f)
                + (nn > 0 ? s_acc[1] / (float)nn : 0.0f);
        if (v != 0.0f) atomicAdd(out, v);
    }
}

extern "C" void kernel_launch(void* const* d_in, const int* in_sizes, int n_in,
                              void* d_out, int out_size, void* d_ws, size_t ws_size,
                              hipStream_t stream) {
    const float* E    = (const float*)d_in[0];
    const int* labels = (const int*)d_in[1];
    const int* graphs = (const int*)d_in[2];
    const int* cats   = (const int*)d_in[3];
    const int* idx1   = (const int*)d_in[4];
    const int* idx2   = (const int*)d_in[5];
    int n = in_sizes[1];   // 8192
    int S = in_sizes[4];   // 5000

    // ws layout (8B-aligned)
    char* p = (char*)d_ws;
    float* invn  = (float*)p;  p += (size_t)n * sizeof(float);
    int* paircnt = (int*)p;    p += sizeof(int);
    int* negcnt  = (int*)p;    p += sizeof(int);
    int2* pairs  = (int2*)p;   p += (size_t)PAIR_CAP * sizeof(int2);
    int2* negp   = (int2*)p;
    float* out   = (float*)d_out;

    zero_kernel<<<1, 1, 0, stream>>>(paircnt, negcnt);
    prep_kernel<<<NB_A, TPB, 0, stream>>>(E, labels, graphs, cats, idx1, idx2,
                                          n, S, invn, paircnt, pairs,
                                          negcnt, negp, out);
    dots_kernel<<<NB_B, TPB, 0, stream>>>(E, invn, paircnt, pairs,
                                          negcnt, negp, out);
}

// Round 8
// 26.585 us; speedup vs baseline: 1.2836x; 1.2836x over previous
//
#include <hip/hip_runtime.h>

#define DIM 512
#define NVEC4 (DIM / 4)     // 128 float4 per row
#define LMAX 512            // labels in [0, 512)
#define MAXB 32             // cap on conserved rows per label (mean ~8, P(>32) ~ 1e-10)
#define MAXPAIR (MAXB * (MAXB - 1) / 2)   // 496
#define TPB 1024
#define NGROUPS (TPB / 16)  // 64 16-lane dot groups per block
#define EPS 1e-12f
#define MAGIC 0x5AFEC0DE

__device__ __forceinline__ float d4(const float4 a, const float4 b) {
    return a.x * b.x + a.y * b.y + a.z * b.z + a.w * b.w;
}

// Publish this block's partial {ps, pc, ns, nc} into slot `bid` (release).
__device__ __forceinline__ void publish(float4* __restrict__ pay,
                                        int* __restrict__ magics, int bid,
                                        float ps, float pc, float ns, float nc) {
    float* pf = (float*)&pay[bid];
    atomicExch(pf + 0, ps);
    atomicExch(pf + 1, pc);
    atomicExch(pf + 2, ns);
    atomicExch(pf + 3, nc);
    __threadfence();
    atomicExch(&magics[bid], MAGIC);
}

// Blocks [0, LMAX): per-label scan -> pair dots (rinv precomputed).
// Blocks [LMAX, grid-1): one 16-lane group per negative sample.
// Block grid-1: spin-consume all slots, reduce, write out. No pre-zeroed state.
__global__ void __launch_bounds__(TPB)
mega_kernel(const float* __restrict__ E,
            const int* __restrict__ labels,
            const int* __restrict__ graphs,
            const int* __restrict__ cats,
            const int* __restrict__ idx1,
            const int* __restrict__ idx2,
            int n, int S, int nslots,
            float4* __restrict__ pay,
            int* __restrict__ magics,
            float* __restrict__ out) {
    __shared__ int idxs[MAXB];
    __shared__ float rinv[MAXB];
    __shared__ int plist[MAXPAIR];     // packed (a<<5)|b
    __shared__ int gcount, pcount;
    __shared__ float s_acc[2];
    const int tid = threadIdx.x;
    const int grp = tid >> 4, gl = tid & 15;
    const int bid = blockIdx.x;
    const float4* E4 = (const float4*)E;

    if (bid < LMAX) {
        // ---------------- positive-pair block for label `bid` ----------------
        if (tid == 0) { gcount = 0; pcount = 0; }
        if (tid < 2) s_acc[tid] = 0.0f;
        __syncthreads();

        const int lbl = bid;
        const int4* lab4 = (const int4*)labels;
        int nv4 = n >> 2;
        for (int v = tid; v < nv4; v += TPB) {
            int4 l4 = lab4[v];
            int base = v << 2;
            if (l4.x == lbl && cats[base + 0] < 3) { int p = atomicAdd(&gcount, 1); if (p < MAXB) idxs[p] = base + 0; }
            if (l4.y == lbl && cats[base + 1] < 3) { int p = atomicAdd(&gcount, 1); if (p < MAXB) idxs[p] = base + 1; }
            if (l4.z == lbl && cats[base + 2] < 3) { int p = atomicAdd(&gcount, 1); if (p < MAXB) idxs[p] = base + 2; }
            if (l4.w == lbl && cats[base + 3] < 3) { int p = atomicAdd(&gcount, 1); if (p < MAXB) idxs[p] = base + 3; }
        }
        __syncthreads();

        const int g = min(gcount, MAXB);
        // enumerate valid pairs (g*g <= 1024 = TPB: one cell per thread)
        if (tid < g * g) {
            int a = tid / g, b = tid - a * g;
            if (a < b && graphs[idxs[a]] != graphs[idxs[b]])
                plist[atomicAdd(&pcount, 1)] = (a << 5) | b;
        }
        // per-row inverse norms (group r handles row r), from global (L2-hot)
        if (grp < g) {
            const float4* A = E4 + (size_t)idxs[grp] * NVEC4;
            float s = 0.0f;
#pragma unroll
            for (int k = 0; k < 8; ++k) { float4 x = A[gl + 16 * k]; s += d4(x, x); }
#pragma unroll
            for (int m = 8; m >= 1; m >>= 1) s += __shfl_xor(s, m, 64);
            if (gl == 0) rinv[grp] = 1.0f / fmaxf(sqrtf(s), EPS);
        }
        __syncthreads();

        const int np = pcount;
        float psum = 0.0f;
        for (int p = grp; p < np; p += NGROUPS) {
            int pk = plist[p];
            int a = pk >> 5, b = pk & 31;
            const float4* A = E4 + (size_t)idxs[a] * NVEC4;
            const float4* B = E4 + (size_t)idxs[b] * NVEC4;
            float ab = 0.0f;
#pragma unroll
            for (int k = 0; k < 8; ++k) ab += d4(A[gl + 16 * k], B[gl + 16 * k]);
#pragma unroll
            for (int m = 8; m >= 1; m >>= 1) ab += __shfl_xor(ab, m, 64);
            if (gl == 0) psum += 1.0f - ab * rinv[a] * rinv[b];
        }
        if (gl == 0 && psum != 0.0f) atomicAdd(&s_acc[0], psum);
        __syncthreads();
        if (tid == 0) publish(pay, magics, bid, s_acc[0], (float)np, 0.0f, 0.0f);

    } else if (bid < nslots) {
        // ---------------- negative-sample block ----------------
        if (tid < 2) s_acc[tid] = 0.0f;
        __syncthreads();

        int s = (bid - LMAX) * NGROUPS + grp;
        float nsum = 0.0f, ncv = 0.0f;
        if (s < S) {
            int i = idx1[s], j = idx2[s];
            if (graphs[i] != graphs[j] && labels[i] != labels[j] &&
                (cats[i] < 3 || cats[j] < 3)) {
                const float4* A = E4 + (size_t)i * NVEC4;
                const float4* B = E4 + (size_t)j * NVEC4;
                float saa = 0.0f, sab = 0.0f, sbb = 0.0f;
#pragma unroll
                for (int k = 0; k < 8; ++k) {
                    float4 x = A[gl + 16 * k], y = B[gl + 16 * k];
                    saa += d4(x, x); sab += d4(x, y); sbb += d4(y, y);
                }
#pragma unroll
                for (int m = 8; m >= 1; m >>= 1) {
                    saa += __shfl_xor(saa, m, 64);
                    sab += __shfl_xor(sab, m, 64);
                    sbb += __shfl_xor(sbb, m, 64);
                }
                if (gl == 0) {
                    float sim = sab / (fmaxf(sqrtf(saa), EPS) * fmaxf(sqrtf(sbb), EPS));
                    nsum = fmaxf(sim, 0.0f);   // MARGIN = 0
                    ncv = 1.0f;
                }
            }
        }
        if (gl == 0 && ncv != 0.0f) {
            atomicAdd(&s_acc[0], nsum);
            atomicAdd(&s_acc[1], ncv);
        }
        __syncthreads();
        if (tid == 0) publish(pay, magics, bid, 0.0f, 0.0f, s_acc[0], s_acc[1]);

    } else {
        // ---------------- finalizer block: consume all slots ----------------
        if (tid < 64) {
            float ps = 0.0f, pc = 0.0f, ns = 0.0f, nc = 0.0f;
            for (int s = tid; s < nslots; s += 64) {
                while (atomicCAS(&magics[s], MAGIC, 0) != MAGIC)
                    __builtin_amdgcn_s_sleep(2);
                __threadfence();
                float* pf = (float*)&pay[s];
                ps += atomicAdd(pf + 0, 0.0f);
                pc += atomicAdd(pf + 1, 0.0f);
                ns += atomicAdd(pf + 2, 0.0f);
                nc += atomicAdd(pf + 3, 0.0f);
            }
#pragma unroll
            for (int m = 32; m > 0; m >>= 1) {
                ps += __shfl_xor(ps, m, 64);
                pc += __shfl_xor(pc, m, 64);
                ns += __shfl_xor(ns, m, 64);
                nc += __shfl_xor(nc, m, 64);
            }
            if (tid == 0) {
                float pos = (pc > 0.0f) ? ps / pc : 0.0f;
                float neg = (nc > 0.0f) ? ns / nc : 0.0f;
                out[0] = pos + neg;
            }
        }
    }
}

extern "C" void kernel_launch(void* const* d_in, const int* in_sizes, int n_in,
                              void* d_out, int out_size, void* d_ws, size_t ws_size,
                              hipStream_t stream) {
    const float* E    = (const float*)d_in[0];
    const int* labels = (const int*)d_in[1];
    const int* graphs = (const int*)d_in[2];
    const int* cats   = (const int*)d_in[3];
    const int* idx1   = (const int*)d_in[4];
    const int* idx2   = (const int*)d_in[5];
    int n = in_sizes[1];   // 8192
    int S = in_sizes[4];   // 5000

    int nb_neg = (S + NGROUPS - 1) / NGROUPS;   // 79: one sample per group
    int nslots = LMAX + nb_neg;                 // worker blocks
    int nb = nslots + 1;                        // + finalizer block

    float4* pay = (float4*)d_ws;                          // nslots payload slots
    int* magics = (int*)((char*)d_ws + (size_t)nslots * sizeof(float4));

    mega_kernel<<<nb, TPB, 0, stream>>>(E, labels, graphs, cats, idx1, idx2,
                                        n, S, nslots, pay, magics, (float*)d_out);
}

// Round 9
// 23.748 us; speedup vs baseline: 1.4369x; 1.1195x over previous
//
#include <hip/hip_runtime.h>

#define DIM 512
#define NVEC4 (DIM / 4)     // 128 float4 per row
#define LMAX 512            // labels in [0, 512)
#define MAXB 32             // cap on conserved rows per label (mean ~8, P(>32) ~ 1e-10)
#define MAXPAIR (MAXB * (MAXB - 1) / 2)   // 496
#define TPB 1024
#define NGROUPS (TPB / 16)  // 64 16-lane dot groups per block
#define EPS 1e-12f
#define MAGIC 0x5AFEC0DE

__device__ __forceinline__ float d4(const float4 a, const float4 b) {
    return a.x * b.x + a.y * b.y + a.z * b.z + a.w * b.w;
}

// Publish this block's partial {ps, pc, ns, nc} into slot `bid` (release).
__device__ __forceinline__ void publish(float4* __restrict__ pay,
                                        int* __restrict__ magics, int bid,
                                        float ps, float pc, float ns, float nc) {
    float* pf = (float*)&pay[bid];
    atomicExch(pf + 0, ps);
    atomicExch(pf + 1, pc);
    atomicExch(pf + 2, ns);
    atomicExch(pf + 3, nc);
    __threadfence();
    atomicExch(&magics[bid], MAGIC);
}

// Blocks [0, LMAX): per-label scan -> pair dots (rinv precomputed).
// Blocks [LMAX, nslots): one 16-lane group per negative sample.
// Block nslots (last): one thread per slot spin-consumes, LDS block-reduce, write out.
// Protocol is initialization-free: magic is CAS-consumed to 0 each call.
__global__ void __launch_bounds__(TPB)
mega_kernel(const float* __restrict__ E,
            const int* __restrict__ labels,
            const int* __restrict__ graphs,
            const int* __restrict__ cats,
            const int* __restrict__ idx1,
            const int* __restrict__ idx2,
            int n, int S, int nslots,
            float4* __restrict__ pay,
            int* __restrict__ magics,
            float* __restrict__ out) {
    __shared__ int idxs[MAXB];
    __shared__ float rinv[MAXB];
    __shared__ int plist[MAXPAIR];     // packed (a<<5)|b
    __shared__ int gcount, pcount;
    __shared__ float s_acc[2];
    __shared__ float red[4][16];       // finalizer wave-partial reduce
    const int tid = threadIdx.x;
    const int grp = tid >> 4, gl = tid & 15;
    const int bid = blockIdx.x;
    const float4* E4 = (const float4*)E;

    if (bid < LMAX) {
        // ---------------- positive-pair block for label `bid` ----------------
        if (tid == 0) { gcount = 0; pcount = 0; }
        if (tid < 2) s_acc[tid] = 0.0f;
        __syncthreads();

        const int lbl = bid;
        const int4* lab4 = (const int4*)labels;
        int nv4 = n >> 2;
        for (int v = tid; v < nv4; v += TPB) {
            int4 l4 = lab4[v];
            int base = v << 2;
            if (l4.x == lbl && cats[base + 0] < 3) { int p = atomicAdd(&gcount, 1); if (p < MAXB) idxs[p] = base + 0; }
            if (l4.y == lbl && cats[base + 1] < 3) { int p = atomicAdd(&gcount, 1); if (p < MAXB) idxs[p] = base + 1; }
            if (l4.z == lbl && cats[base + 2] < 3) { int p = atomicAdd(&gcount, 1); if (p < MAXB) idxs[p] = base + 2; }
            if (l4.w == lbl && cats[base + 3] < 3) { int p = atomicAdd(&gcount, 1); if (p < MAXB) idxs[p] = base + 3; }
        }
        __syncthreads();

        const int g = min(gcount, MAXB);
        // enumerate valid pairs (g*g <= 1024 = TPB: one cell per thread)
        if (tid < g * g) {
            int a = tid / g, b = tid - a * g;
            if (a < b && graphs[idxs[a]] != graphs[idxs[b]])
                plist[atomicAdd(&pcount, 1)] = (a << 5) | b;
        }
        // per-row inverse norms (group r handles row r), global reads (L2-hot)
        if (grp < g) {
            const float4* A = E4 + (size_t)idxs[grp] * NVEC4;
            float s = 0.0f;
#pragma unroll
            for (int k = 0; k < 8; ++k) { float4 x = A[gl + 16 * k]; s += d4(x, x); }
#pragma unroll
            for (int m = 8; m >= 1; m >>= 1) s += __shfl_xor(s, m, 64);
            if (gl == 0) rinv[grp] = 1.0f / fmaxf(sqrtf(s), EPS);
        }
        __syncthreads();

        const int np = pcount;
        float psum = 0.0f;
        for (int p = grp; p < np; p += NGROUPS) {
            int pk = plist[p];
            int a = pk >> 5, b = pk & 31;
            const float4* A = E4 + (size_t)idxs[a] * NVEC4;
            const float4* B = E4 + (size_t)idxs[b] * NVEC4;
            float ab = 0.0f;
#pragma unroll
            for (int k = 0; k < 8; ++k) ab += d4(A[gl + 16 * k], B[gl + 16 * k]);
#pragma unroll
            for (int m = 8; m >= 1; m >>= 1) ab += __shfl_xor(ab, m, 64);
            if (gl == 0) psum += 1.0f - ab * rinv[a] * rinv[b];
        }
        if (gl == 0 && psum != 0.0f) atomicAdd(&s_acc[0], psum);
        __syncthreads();
        if (tid == 0) publish(pay, magics, bid, s_acc[0], (float)np, 0.0f, 0.0f);

    } else if (bid < nslots) {
        // ---------------- negative-sample block ----------------
        if (tid < 2) s_acc[tid] = 0.0f;
        __syncthreads();

        int s = (bid - LMAX) * NGROUPS + grp;
        float nsum = 0.0f, ncv = 0.0f;
        if (s < S) {
            int i = idx1[s], j = idx2[s];
            if (graphs[i] != graphs[j] && labels[i] != labels[j] &&
                (cats[i] < 3 || cats[j] < 3)) {
                const float4* A = E4 + (size_t)i * NVEC4;
                const float4* B = E4 + (size_t)j * NVEC4;
                float saa = 0.0f, sab = 0.0f, sbb = 0.0f;
#pragma unroll
                for (int k = 0; k < 8; ++k) {
                    float4 x = A[gl + 16 * k], y = B[gl + 16 * k];
                    saa += d4(x, x); sab += d4(x, y); sbb += d4(y, y);
                }
#pragma unroll
                for (int m = 8; m >= 1; m >>= 1) {
                    saa += __shfl_xor(saa, m, 64);
                    sab += __shfl_xor(sab, m, 64);
                    sbb += __shfl_xor(sbb, m, 64);
                }
                if (gl == 0) {
                    float sim = sab / (fmaxf(sqrtf(saa), EPS) * fmaxf(sqrtf(sbb), EPS));
                    nsum = fmaxf(sim, 0.0f);   // MARGIN = 0
                    ncv = 1.0f;
                }
            }
        }
        if (gl == 0 && ncv != 0.0f) {
            atomicAdd(&s_acc[0], nsum);
            atomicAdd(&s_acc[1], ncv);
        }
        __syncthreads();
        if (tid == 0) publish(pay, magics, bid, 0.0f, 0.0f, s_acc[0], s_acc[1]);

    } else {
        // -------- finalizer block: one thread per slot, parallel consume --------
        float ps = 0.0f, pc = 0.0f, ns = 0.0f, nc = 0.0f;
        if (tid < nslots) {
            while (atomicCAS(&magics[tid], MAGIC, 0) != MAGIC)
                __builtin_amdgcn_s_sleep(8);
            __threadfence();
            float* pf = (float*)&pay[tid];
            ps = atomicAdd(pf + 0, 0.0f);
            pc = atomicAdd(pf + 1, 0.0f);
            ns = atomicAdd(pf + 2, 0.0f);
            nc = atomicAdd(pf + 3, 0.0f);
        }
#pragma unroll
        for (int m = 32; m > 0; m >>= 1) {
            ps += __shfl_xor(ps, m, 64);
            pc += __shfl_xor(pc, m, 64);
            ns += __shfl_xor(ns, m, 64);
            nc += __shfl_xor(nc, m, 64);
        }
        int wid = tid >> 6;
        if ((tid & 63) == 0) {
            red[0][wid] = ps; red[1][wid] = pc; red[2][wid] = ns; red[3][wid] = nc;
        }
        __syncthreads();
        if (tid < 16) {
            ps = red[0][tid]; pc = red[1][tid]; ns = red[2][tid]; nc = red[3][tid];
#pragma unroll
            for (int m = 8; m >= 1; m >>= 1) {
                ps += __shfl_xor(ps, m, 64);
                pc += __shfl_xor(pc, m, 64);
                ns += __shfl_xor(ns, m, 64);
                nc += __shfl_xor(nc, m, 64);
            }
            if (tid == 0) {
                float pos = (pc > 0.0f) ? ps / pc : 0.0f;
                float neg = (nc > 0.0f) ? ns / nc : 0.0f;
                out[0] = pos + neg;
            }
        }
    }
}

extern "C" void kernel_launch(void* const* d_in, const int* in_sizes, int n_in,
                              void* d_out, int out_size, void* d_ws, size_t ws_size,
                              hipStream_t stream) {
    const float* E    = (const float*)d_in[0];
    const int* labels = (const int*)d_in[1];
    const int* graphs = (const int*)d_in[2];
    const int* cats   = (const int*)d_in[3];
    const int* idx1   = (const int*)d_in[4];
    const int* idx2   = (const int*)d_in[5];
    int n = in_sizes[1];   // 8192
    int S = in_sizes[4];   // 5000

    int nb_neg = (S + NGROUPS - 1) / NGROUPS;   // 79: one sample per group
    int nslots = LMAX + nb_neg;                 // worker blocks (591 <= TPB)
    int nb = nslots + 1;                        // + finalizer block

    float4* pay = (float4*)d_ws;                          // nslots payload slots
    int* magics = (int*)((char*)d_ws + (size_t)nslots * sizeof(float4));

    mega_kernel<<<nb, TPB, 0, stream>>>(E, labels, graphs, cats, idx1, idx2,
                                        n, S, nslots, pay, magics, (float*)d_out);
}

// Round 10
// 18.110 us; speedup vs baseline: 1.8843x; 1.3113x over previous
//
#include <hip/hip_runtime.h>

#define DIM 512
#define NVEC4 (DIM / 4)     // 128 float4 per row
#define LMAX 512            // labels in [0, 512)
#define MAXB 32             // cap on conserved rows per label (mean ~8, P(>32) ~ 1e-10)
#define MAXPAIR (MAXB * (MAXB - 1) / 2)   // 496
#define TPB 1024
#define NGROUPS (TPB / 16)  // 64 16-lane dot groups per block
#define EPS 1e-12f

__device__ __forceinline__ float d4(const float4 a, const float4 b) {
    return a.x * b.x + a.y * b.y + a.z * b.z + a.w * b.w;
}

// Grid = exactly LMAX(512) blocks of 1024 threads -> one fully-resident wave
// (2 blocks/CU x 256 CUs). Block bid:
//   - groups with grp*LMAX+bid < S each handle one negative sample
//   - whole block scans label==bid conserved rows, enumerates valid pairs,
//     precomputes rinv[], then 64 groups sweep the pair list (ab-only reduce).
// Block writes partials[bid] = {psum, pcnt, nsum, ncnt} unconditionally.
__global__ void __launch_bounds__(TPB)
mega_kernel(const float* __restrict__ E,
            const int* __restrict__ labels,
            const int* __restrict__ graphs,
            const int* __restrict__ cats,
            const int* __restrict__ idx1,
            const int* __restrict__ idx2,
            int n, int S,
            float4* __restrict__ partials) {
    __shared__ int idxs[MAXB];
    __shared__ float rinv[MAXB];
    __shared__ int plist[MAXPAIR];     // packed (a<<5)|b
    __shared__ int gcount, pcount;
    __shared__ float s_acc[3];         // psum, nsum, ncnt
    const int tid = threadIdx.x;
    const int grp = tid >> 4, gl = tid & 15;
    const int bid = blockIdx.x;
    const float4* E4 = (const float4*)E;

    if (tid == 0) { gcount = 0; pcount = 0; }
    if (tid < 3) s_acc[tid] = 0.0f;
    __syncthreads();

    // ---- negative sample for this group (<=1 per group) ----
    {
        int s = grp * LMAX + bid;
        if (s < S) {
            int i = idx1[s], j = idx2[s];
            if (graphs[i] != graphs[j] && labels[i] != labels[j] &&
                (cats[i] < 3 || cats[j] < 3)) {
                const float4* A = E4 + (size_t)i * NVEC4;
                const float4* B = E4 + (size_t)j * NVEC4;
                float saa = 0.0f, sab = 0.0f, sbb = 0.0f;
#pragma unroll
                for (int k = 0; k < 8; ++k) {
                    float4 x = A[gl + 16 * k], y = B[gl + 16 * k];
                    saa += d4(x, x); sab += d4(x, y); sbb += d4(y, y);
                }
#pragma unroll
                for (int m = 8; m >= 1; m >>= 1) {
                    saa += __shfl_xor(saa, m, 64);
                    sab += __shfl_xor(sab, m, 64);
                    sbb += __shfl_xor(sbb, m, 64);
                }
                if (gl == 0) {
                    float sim = sab / (fmaxf(sqrtf(saa), EPS) * fmaxf(sqrtf(sbb), EPS));
                    atomicAdd(&s_acc[1], fmaxf(sim, 0.0f));   // MARGIN = 0
                    atomicAdd(&s_acc[2], 1.0f);
                }
            }
        }
    }

    // ---- scan: conserved rows with label == bid (int4-vectorized labels) ----
    {
        const int lbl = bid;
        const int4* lab4 = (const int4*)labels;
        int nv4 = n >> 2;
        for (int v = tid; v < nv4; v += TPB) {
            int4 l4 = lab4[v];
            int base = v << 2;
            if (l4.x == lbl && cats[base + 0] < 3) { int p = atomicAdd(&gcount, 1); if (p < MAXB) idxs[p] = base + 0; }
            if (l4.y == lbl && cats[base + 1] < 3) { int p = atomicAdd(&gcount, 1); if (p < MAXB) idxs[p] = base + 1; }
            if (l4.z == lbl && cats[base + 2] < 3) { int p = atomicAdd(&gcount, 1); if (p < MAXB) idxs[p] = base + 2; }
            if (l4.w == lbl && cats[base + 3] < 3) { int p = atomicAdd(&gcount, 1); if (p < MAXB) idxs[p] = base + 3; }
        }
    }
    __syncthreads();

    const int g = min(gcount, MAXB);
    // ---- enumerate valid pairs (g*g <= 1024 = TPB: one cell per thread) ----
    if (tid < g * g) {
        int a = tid / g, b = tid - a * g;
        if (a < b && graphs[idxs[a]] != graphs[idxs[b]])
            plist[atomicAdd(&pcount, 1)] = (a << 5) | b;
    }
    // ---- per-row inverse norms (group r handles row r), L2-hot reads ----
    if (grp < g) {
        const float4* A = E4 + (size_t)idxs[grp] * NVEC4;
        float s = 0.0f;
#pragma unroll
        for (int k = 0; k < 8; ++k) { float4 x = A[gl + 16 * k]; s += d4(x, x); }
#pragma unroll
        for (int m = 8; m >= 1; m >>= 1) s += __shfl_xor(s, m, 64);
        if (gl == 0) rinv[grp] = 1.0f / fmaxf(sqrtf(s), EPS);
    }
    __syncthreads();

    // ---- pair dots: 64 concurrent 16-lane groups, ab-only reduce ----
    const int np = pcount;
    float psum = 0.0f;
    for (int p = grp; p < np; p += NGROUPS) {
        int pk = plist[p];
        int a = pk >> 5, b = pk & 31;
        const float4* A = E4 + (size_t)idxs[a] * NVEC4;
        const float4* B = E4 + (size_t)idxs[b] * NVEC4;
        float ab = 0.0f;
#pragma unroll
        for (int k = 0; k < 8; ++k) ab += d4(A[gl + 16 * k], B[gl + 16 * k]);
#pragma unroll
        for (int m = 8; m >= 1; m >>= 1) ab += __shfl_xor(ab, m, 64);
        if (gl == 0) psum += 1.0f - ab * rinv[a] * rinv[b];
    }
    if (gl == 0 && psum != 0.0f) atomicAdd(&s_acc[0], psum);
    __syncthreads();

    if (tid == 0)
        partials[bid] = make_float4(s_acc[0], (float)np, s_acc[1], s_acc[2]);
}

__global__ void __launch_bounds__(64)
finalize_kernel(const float4* __restrict__ partials, int nb,
                float* __restrict__ out) {
    int lane = threadIdx.x;
    float ps = 0.0f, pc = 0.0f, ns = 0.0f, nc = 0.0f;
    for (int i = lane; i < nb; i += 64) {
        float4 v = partials[i];
        ps += v.x; pc += v.y; ns += v.z; nc += v.w;
    }
#pragma unroll
    for (int m = 32; m > 0; m >>= 1) {
        ps += __shfl_xor(ps, m, 64);
        pc += __shfl_xor(pc, m, 64);
        ns += __shfl_xor(ns, m, 64);
        nc += __shfl_xor(nc, m, 64);
    }
    if (lane == 0) {
        float pos = (pc > 0.0f) ? ps / pc : 0.0f;
        float neg = (nc > 0.0f) ? ns / nc : 0.0f;
        out[0] = pos + neg;
    }
}

extern "C" void kernel_launch(void* const* d_in, const int* in_sizes, int n_in,
                              void* d_out, int out_size, void* d_ws, size_t ws_size,
                              hipStream_t stream) {
    const float* E    = (const float*)d_in[0];
    const int* labels = (const int*)d_in[1];
    const int* graphs = (const int*)d_in[2];
    const int* cats   = (const int*)d_in[3];
    const int* idx1   = (const int*)d_in[4];
    const int* idx2   = (const int*)d_in[5];
    int n = in_sizes[1];   // 8192
    int S = in_sizes[4];   // 5000

    float4* partials = (float4*)d_ws;   // LMAX slots, all written every call

    mega_kernel<<<LMAX, TPB, 0, stream>>>(E, labels, graphs, cats,
                                          idx1, idx2, n, S, partials);
    finalize_kernel<<<1, 64, 0, stream>>>(partials, LMAX, (float*)d_out);
}

// Round 11
// 17.540 us; speedup vs baseline: 1.9455x; 1.0325x over previous
//
#include <hip/hip_runtime.h>

#define DIM 512
#define NVEC4 (DIM / 4)     // 128 float4 per row
#define LMAX 512            // labels in [0, 512)
#define MAXB 32             // cap on conserved rows per label (mean ~8, P(>32) ~ 1e-10)
#define MAXPAIR (MAXB * (MAXB - 1) / 2)   // 496
#define TPB 1024
#define NG16 (TPB / 16)     // 64 16-lane groups (neg samples)
#define NG8  (TPB / 8)      // 128 8-lane groups (pair dots, rinv)
#define EPS 1e-12f

__device__ __forceinline__ float d4(const float4 a, const float4 b) {
    return a.x * b.x + a.y * b.y + a.z * b.z + a.w * b.w;
}

// Grid = exactly LMAX(512) blocks of 1024 threads -> one fully-resident wave
// (2 blocks/CU x 256 CUs). Block bid:
//   - 16-lane groups with g16*LMAX+bid < S each handle one negative sample
//   - block scans label==bid conserved rows, enumerates valid pairs,
//     computes rinv[] (8-lane groups), then 128 8-lane groups sweep the
//     pair list (ab-only reduce, 3 shfls).
// Block writes partials[bid] = {psum, pcnt, nsum, ncnt} unconditionally.
__global__ void __launch_bounds__(TPB)
mega_kernel(const float* __restrict__ E,
            const int* __restrict__ labels,
            const int* __restrict__ graphs,
            const int* __restrict__ cats,
            const int* __restrict__ idx1,
            const int* __restrict__ idx2,
            int n, int S,
            float4* __restrict__ partials) {
    __shared__ int idxs[MAXB];
    __shared__ float rinv[MAXB];
    __shared__ int plist[MAXPAIR];     // packed (a<<5)|b
    __shared__ int gcount, pcount;
    __shared__ float s_acc[3];         // psum, nsum, ncnt
    const int tid = threadIdx.x;
    const int g16 = tid >> 4, l16 = tid & 15;
    const int g8  = tid >> 3, l8  = tid & 7;
    const int bid = blockIdx.x;
    const float4* E4 = (const float4*)E;

    if (tid == 0) { gcount = 0; pcount = 0; }
    if (tid < 3) s_acc[tid] = 0.0f;
    __syncthreads();

    // ---- negative sample for this 16-lane group (<=1 per group) ----
    {
        int s = g16 * LMAX + bid;
        if (s < S) {
            int i = idx1[s], j = idx2[s];
            if (graphs[i] != graphs[j] && labels[i] != labels[j] &&
                (cats[i] < 3 || cats[j] < 3)) {
                const float4* A = E4 + (size_t)i * NVEC4;
                const float4* B = E4 + (size_t)j * NVEC4;
                float saa = 0.0f, sab = 0.0f, sbb = 0.0f;
#pragma unroll
                for (int k = 0; k < 8; ++k) {
                    float4 x = A[l16 + 16 * k], y = B[l16 + 16 * k];
                    saa += d4(x, x); sab += d4(x, y); sbb += d4(y, y);
                }
#pragma unroll
                for (int m = 8; m >= 1; m >>= 1) {
                    saa += __shfl_xor(saa, m, 64);
                    sab += __shfl_xor(sab, m, 64);
                    sbb += __shfl_xor(sbb, m, 64);
                }
                if (l16 == 0) {
                    float sim = sab / (fmaxf(sqrtf(saa), EPS) * fmaxf(sqrtf(sbb), EPS));
                    atomicAdd(&s_acc[1], fmaxf(sim, 0.0f));   // MARGIN = 0
                    atomicAdd(&s_acc[2], 1.0f);
                }
            }
        }
    }

    // ---- scan: conserved rows with label == bid (int4-vectorized labels) ----
    {
        const int lbl = bid;
        const int4* lab4 = (const int4*)labels;
        int nv4 = n >> 2;
        for (int v = tid; v < nv4; v += TPB) {
            int4 l4 = lab4[v];
            int base = v << 2;
            if (l4.x == lbl && cats[base + 0] < 3) { int p = atomicAdd(&gcount, 1); if (p < MAXB) idxs[p] = base + 0; }
            if (l4.y == lbl && cats[base + 1] < 3) { int p = atomicAdd(&gcount, 1); if (p < MAXB) idxs[p] = base + 1; }
            if (l4.z == lbl && cats[base + 2] < 3) { int p = atomicAdd(&gcount, 1); if (p < MAXB) idxs[p] = base + 2; }
            if (l4.w == lbl && cats[base + 3] < 3) { int p = atomicAdd(&gcount, 1); if (p < MAXB) idxs[p] = base + 3; }
        }
    }
    __syncthreads();

    const int g = min(gcount, MAXB);
    // ---- per-row inverse norms: 8-lane group r handles row r ----
    if (g8 < g) {
        const float4* A = E4 + (size_t)idxs[g8] * NVEC4;
        float s = 0.0f;
#pragma unroll
        for (int k = 0; k < 16; ++k) { float4 x = A[l8 + 8 * k]; s += d4(x, x); }
#pragma unroll
        for (int m = 4; m >= 1; m >>= 1) s += __shfl_xor(s, m, 64);
        if (l8 == 0) rinv[g8] = 1.0f / fmaxf(sqrtf(s), EPS);
    }
    // ---- enumerate valid pairs (g*g <= 1024 = TPB: one cell per thread) ----
    if (tid < g * g) {
        int a = tid / g, b = tid - a * g;
        if (a < b && graphs[idxs[a]] != graphs[idxs[b]])
            plist[atomicAdd(&pcount, 1)] = (a << 5) | b;
    }
    __syncthreads();

    // ---- pair dots: 128 concurrent 8-lane groups, ab-only reduce ----
    const int np = pcount;
    float psum = 0.0f;
    for (int p = g8; p < np; p += NG8) {
        int pk = plist[p];
        int a = pk >> 5, b = pk & 31;
        const float4* A = E4 + (size_t)idxs[a] * NVEC4;
        const float4* B = E4 + (size_t)idxs[b] * NVEC4;
        float ab = 0.0f;
#pragma unroll
        for (int k = 0; k < 16; ++k) ab += d4(A[l8 + 8 * k], B[l8 + 8 * k]);
#pragma unroll
        for (int m = 4; m >= 1; m >>= 1) ab += __shfl_xor(ab, m, 64);
        if (l8 == 0) psum += 1.0f - ab * rinv[a] * rinv[b];
    }
    if (l8 == 0 && psum != 0.0f) atomicAdd(&s_acc[0], psum);
    __syncthreads();

    if (tid == 0)
        partials[bid] = make_float4(s_acc[0], (float)np, s_acc[1], s_acc[2]);
}

__global__ void __launch_bounds__(256)
finalize_kernel(const float4* __restrict__ partials, int nb,
                float* __restrict__ out) {
    __shared__ float red[4][4];
    int tid = threadIdx.x, lane = tid & 63, wid = tid >> 6;
    float ps = 0.0f, pc = 0.0f, ns = 0.0f, nc = 0.0f;
    for (int i = tid; i < nb; i += 256) {
        float4 v = partials[i];
        ps += v.x; pc += v.y; ns += v.z; nc += v.w;
    }
#pragma unroll
    for (int m = 32; m > 0; m >>= 1) {
        ps += __shfl_xor(ps, m, 64);
        pc += __shfl_xor(pc, m, 64);
        ns += __shfl_xor(ns, m, 64);
        nc += __shfl_xor(nc, m, 64);
    }
    if (lane == 0) { red[0][wid] = ps; red[1][wid] = pc; red[2][wid] = ns; red[3][wid] = nc; }
    __syncthreads();
    if (tid == 0) {
        ps = red[0][0] + red[0][1] + red[0][2] + red[0][3];
        pc = red[1][0] + red[1][1] + red[1][2] + red[1][3];
        ns = red[2][0] + red[2][1] + red[2][2] + red[2][3];
        nc = red[3][0] + red[3][1] + red[3][2] + red[3][3];
        float pos = (pc > 0.0f) ? ps / pc : 0.0f;
        float neg = (nc > 0.0f) ? ns / nc : 0.0f;
        out[0] = pos + neg;
    }
}

extern "C" void kernel_launch(void* const* d_in, const int* in_sizes, int n_in,
                              void* d_out, int out_size, void* d_ws, size_t ws_size,
                              hipStream_t stream) {
    const float* E    = (const float*)d_in[0];
    const int* labels = (const int*)d_in[1];
    const int* graphs = (const int*)d_in[2];
    const int* cats   = (const int*)d_in[3];
    const int* idx1   = (const int*)d_in[4];
    const int* idx2   = (const int*)d_in[5];
    int n = in_sizes[1];   // 8192
    int S = in_sizes[4];   // 5000

    float4* partials = (float4*)d_ws;   // LMAX slots, all written every call

    mega_kernel<<<LMAX, TPB, 0, stream>>>(E, labels, graphs, cats,
                                          idx1, idx2, n, S, partials);
    finalize_kernel<<<1, 256, 0, stream>>>(partials, LMAX, (float*)d_out);
}